// Round 12
// baseline (237.584 us; speedup 1.0000x reference)
//
#include <hip/hip_runtime.h>
#include <hip/hip_fp16.h>

#define NG 512
#define HID 64
#define CSH 9                 // coarse-bucket shift: 512 nodes/bucket
#define BKT (1 << CSH)
#define PTILE 4096            // partA edges per block
#define MAXB 1024             // max coarse buckets (N up to 512k)
#define TNB 64                // layer1f node tile (16KB LDS -> ~6 blocks/CU)

// Each node's CSR segment is padded to a multiple of 8; pad slots hold src=N,
// which indexes a zero row in xs2 / h2, so pads contribute nothing.
__device__ __forceinline__ int pad8(int d) { return (d + 7) & ~7; }

// ---------------- partA: coarse partition into fixed-stride pstage ----------
// pstage entry = (src << CSH) | (dst & (BKT-1)) : 4B. Fixed per-bucket stride
// S lets buckets claim runs with ONE global atomicAdd on bcnt[]. gstart
// (batch sorted; boundary detection) folded in as latency-filler work.
__global__ __launch_bounds__(256) void partA_kernel(
    const int* __restrict__ src, const int* __restrict__ dst,
    const int* __restrict__ batch, int* __restrict__ gstart,
    int* __restrict__ bcnt, int* __restrict__ pstage,
    int E, int N, int nbc, int S) {
    __shared__ int hist[MAXB];
    __shared__ int base[MAXB];
    int tid = threadIdx.x;
    int t0 = blockIdx.x * PTILE;
    for (int i = blockIdx.x * 256 + tid; i < N; i += gridDim.x * 256) {
        int b = batch[i];
        int bp = (i == 0) ? -1 : batch[i - 1];
        for (int g = bp + 1; g <= b; ++g) gstart[g] = i;   // boundaries only
        if (i == N - 1)
            for (int g = b + 1; g <= NG; ++g) gstart[g] = N;
    }
    for (int i = tid; i < nbc; i += 256) hist[i] = 0;
    __syncthreads();
    int es[PTILE / 256], ds[PTILE / 256];
#pragma unroll
    for (int j = 0; j < PTILE / 256; ++j) {
        int e = t0 + j * 256 + tid;
        if (e < E) {
            ds[j] = dst[e];
            es[j] = src[e];
            atomicAdd(&hist[ds[j] >> CSH], 1);
        } else {
            ds[j] = -1;
        }
    }
    __syncthreads();
    for (int i = tid; i < nbc; i += 256) {
        int c = hist[i];
        base[i] = c ? atomicAdd(&bcnt[i], c) : 0;
        hist[i] = 0;  // reuse as tile-local cursor
    }
    __syncthreads();
#pragma unroll
    for (int j = 0; j < PTILE / 256; ++j) {
        if (ds[j] >= 0) {
            int b = ds[j] >> CSH;
            int r = base[b] + atomicAdd(&hist[b], 1);
            if (r < S)  // guard (never fires for uniform-random dst)
                pstage[(size_t)b * S + r] = (es[j] << CSH) | (ds[j] & (BKT - 1));
        }
    }
}

// ---------------- partB2: per-bucket deg/dinv/xs2 + rowbeg + scatter + pads --
// One block per bucket; single-writer esrc window (no write amplification).
// Also zeroes the h2 pad row (block 0) so the second host memset is gone.
__global__ __launch_bounds__(256) void partB2_kernel(
    const int* __restrict__ pstage, const int* __restrict__ bcnt,
    const float2* __restrict__ x2, int* __restrict__ deg, float* __restrict__ dinv,
    float2* __restrict__ xs2, int* __restrict__ rowbeg, int* __restrict__ esrc,
    int* __restrict__ ecur, __half* __restrict__ h2, int N, int S) {
    __shared__ int h[BKT];
    __shared__ int rowL[BKT];
    __shared__ int curL[BKT];
    __shared__ int ps[256];
    __shared__ int baseS;
    int c = blockIdx.x;
    int n0 = c << CSH;
    int tid = threadIdx.x;
    for (int i = tid; i < BKT; i += 256) h[i] = 0;
    __syncthreads();
    int cnt = min(bcnt[c], S);
    const int* pst = pstage + (size_t)c * S;
    for (int i = tid; i < cnt; i += 256) atomicAdd(&h[pst[i] & (BKT - 1)], 1);
    __syncthreads();
    int i0 = 2 * tid, i1 = 2 * tid + 1;
    int dg0 = (n0 + i0 < N) ? h[i0] : 0;
    int dg1 = (n0 + i1 < N) ? h[i1] : 0;
    if (n0 + i0 < N) {
        deg[n0 + i0] = dg0;
        float di = rsqrtf((float)dg0 + 1.0f);
        dinv[n0 + i0] = di;
        float2 xv = x2[n0 + i0];
        xs2[n0 + i0] = make_float2(xv.x * di, xv.y * di);
    }
    if (n0 + i1 < N) {
        deg[n0 + i1] = dg1;
        float di = rsqrtf((float)dg1 + 1.0f);
        dinv[n0 + i1] = di;
        float2 xv = x2[n0 + i1];
        xs2[n0 + i1] = make_float2(xv.x * di, xv.y * di);
    }
    int p0 = pad8(dg0), p1 = pad8(dg1);
    ps[tid] = p0 + p1;
    __syncthreads();
    for (int off = 1; off < 256; off <<= 1) {
        int t = (tid >= off) ? ps[tid - off] : 0;
        __syncthreads();
        ps[tid] += t;
        __syncthreads();
    }
    if (tid == 255) baseS = atomicAdd(ecur, ps[255]);  // claim bucket's esrc span
    __syncthreads();
    int excl = baseS + ps[tid] - (p0 + p1);
    rowL[i0] = excl;
    rowL[i1] = excl + p0;
    curL[i0] = 0;
    curL[i1] = 0;
    if (n0 + i0 < N) rowbeg[n0 + i0] = rowL[i0];
    if (n0 + i1 < N) rowbeg[n0 + i1] = rowL[i1];
    __syncthreads();
    for (int i = tid; i < cnt; i += 256) {
        int w = pst[i];
        int l = w & (BKT - 1);
        int p = rowL[l] + atomicAdd(&curL[l], 1);
        esrc[p] = w >> CSH;
    }
    __syncthreads();
    for (int l = tid; l < BKT; l += 256) {
        if (n0 + l < N) {
            int dg = curL[l];                  // == deg
            int p = rowL[l] + dg, p1e = rowL[l] + pad8(dg);
            for (; p < p1e; ++p) esrc[p] = N;  // pads -> zero row (<=7 per node)
        }
    }
    if (c == 0) {
        if (tid == 0) xs2[N] = make_float2(0.0f, 0.0f);
        if (tid < 8)  // zero h2 pad row (128B) -> replaces host memset
            ((int4*)(h2 + (size_t)N * HID))[tid] = make_int4(0, 0, 0, 0);
    }
}

// ---------------- layer1f: fused gather+W1 and @W2 (fp16 out) ----------------
// Replaces layer1a + l1gemm, deleting the 51MB h1buf round-trip. Per block of
// 64 nodes: phase 1 = 4 waves x 16 nodes gather (wave-uniform esrc/xs2 loads,
// lane=feature applies W1, relu, *dinv) writing straight into the swizzled
// LDS tile; phase 2 = thread t -> node t&63, jt base (t>>6)*2 (all 256
// threads active), scalarized W2, ascending-k fma order -> bit-identical to
// the R11 pair. TNB=64 (16KB LDS) keeps ~6 blocks/CU so the latency-bound
// gather phase retains layer1a-level MLP (~24 waves/CU x 9 loads in flight).
__global__ __launch_bounds__(256) void layer1f_kernel(
    const float2* __restrict__ xs2, const int* __restrict__ rowbeg,
    const int* __restrict__ deg, const int* __restrict__ esrc,
    const float* __restrict__ dinv, const float* __restrict__ W1,
    const float* __restrict__ b1, const float* __restrict__ W2,
    __half* __restrict__ h2, int N) {
    __shared__ float h1t[HID * TNB];  // 16KB, [k][node ^ (k&31)]
    int tid = threadIdx.x;
    int lane = tid & 63;
    int wv = tid >> 6;
    int node0 = blockIdx.x * TNB;
    // phase 1: gather, 4 waves x 16 nodes each (node wave-uniform)
    for (int j = 0; j < TNB / 4; ++j) {
        int nl = wv * (TNB / 4) + j;
        int node = node0 + nl;
        if (node < N) {
            int un = __builtin_amdgcn_readfirstlane(node);
            int k0 = __builtin_amdgcn_readfirstlane(rowbeg[un]);
            int k1 = k0 + pad8(__builtin_amdgcn_readfirstlane(deg[un]));
            float a0 = 0.0f, a1 = 0.0f;
            for (int e = k0; e < k1; e += 8) {
                const int4* ep = (const int4*)(esrc + e);  // 32B-aligned
                int4 qa = ep[0], qb = ep[1];
                float2 v0 = xs2[qa.x], v1 = xs2[qa.y], v2 = xs2[qa.z], v3 = xs2[qa.w];
                float2 v4 = xs2[qb.x], v5 = xs2[qb.y], v6 = xs2[qb.z], v7 = xs2[qb.w];
                a0 += ((v0.x + v1.x) + (v2.x + v3.x)) + ((v4.x + v5.x) + (v6.x + v7.x));
                a1 += ((v0.y + v1.y) + (v2.y + v3.y)) + ((v4.y + v5.y) + (v6.y + v7.y));
            }
            float di = dinv[un];
            float2 xn = xs2[un];
            float m0 = di * (a0 + xn.x);  // = di*sum(x_s*di_s) + x_n*di^2
            float m1 = di * (a1 + xn.y);
            float v = fmaf(m0, W1[lane], fmaf(m1, W1[HID + lane], b1[lane]));
            // lane = feature k; 2-way bank alias on write (free)
            h1t[lane * TNB + (nl ^ (lane & 31))] = fmaxf(v, 0.0f) * di;
        }
    }
    __syncthreads();
    // phase 2: GEMM. thread t -> node t&63, cols [(t>>6)*16, +16)
    int nd = tid & 63;
    int node = node0 + nd;
    bool alive = node < N;
    int jb = wv * 2;
#pragma unroll
    for (int jt = jb; jt < jb + 2; ++jt) {
        float c0 = 0.f, c1 = 0.f, c2 = 0.f, c3 = 0.f;
        float c4 = 0.f, c5 = 0.f, c6 = 0.f, c7 = 0.f;
#pragma unroll 8
        for (int k = 0; k < HID; ++k) {  // ascending k: same fma order as R11
            float h = h1t[k * TNB + (nd ^ (k & 31))];
            const float4* wr = (const float4*)(W2 + k * HID + jt * 8);  // uniform
            float4 wa = wr[0], wb = wr[1];
            c0 = fmaf(h, wa.x, c0); c1 = fmaf(h, wa.y, c1);
            c2 = fmaf(h, wa.z, c2); c3 = fmaf(h, wa.w, c3);
            c4 = fmaf(h, wb.x, c4); c5 = fmaf(h, wb.y, c5);
            c6 = fmaf(h, wb.z, c6); c7 = fmaf(h, wb.w, c7);
        }
        if (alive) {
            union { __half h[8]; int4 v; } u;
            u.h[0] = __float2half_rn(c0); u.h[1] = __float2half_rn(c1);
            u.h[2] = __float2half_rn(c2); u.h[3] = __float2half_rn(c3);
            u.h[4] = __float2half_rn(c4); u.h[5] = __float2half_rn(c5);
            u.h[6] = __float2half_rn(c6); u.h[7] = __float2half_rn(c7);
            *(int4*)(h2 + (size_t)node * HID + jt * 8) = u.v;
        }
    }
}

// ---------------- layer 2: fp16 gather-sum + graph-run pooled atomics -------
__global__ __launch_bounds__(256, 8) void layer2_kernel(
    const int* __restrict__ rowbeg, const int* __restrict__ deg,
    const int* __restrict__ esrc, const float* __restrict__ dinv,
    const __half* __restrict__ h2, const float* __restrict__ b2,
    const int* __restrict__ batch, float* __restrict__ gsum, int N) {
    int lane = threadIdx.x & 63;
    float bz = b2[lane];
    int wave = (blockIdx.x * 256 + threadIdx.x) >> 6;
    int nwaves = gridDim.x * 4;
    int npw = (N + nwaves - 1) / nwaves;
    int nA = wave * npw;
    int nB = min(N, nA + npw);
    int gcur = -1;
    float zacc = 0.0f;
    for (int node = nA; node < nB; ++node) {
        int un = __builtin_amdgcn_readfirstlane(node);
        int k0 = __builtin_amdgcn_readfirstlane(rowbeg[un]);
        int k1 = k0 + pad8(__builtin_amdgcn_readfirstlane(deg[un]));
        float acc = __half2float(h2[(un << 6) + lane]);  // self term
        int e = k0;
        for (; e + 32 <= k1; e += 32) {
            const int4* ep = (const int4*)(esrc + e);
            int4 q0 = ep[0], q1 = ep[1], q2 = ep[2], q3 = ep[3];
            int4 q4 = ep[4], q5 = ep[5], q6 = ep[6], q7 = ep[7];
            float r0  = __half2float(h2[(q0.x << 6) + lane]);
            float r1  = __half2float(h2[(q0.y << 6) + lane]);
            float r2  = __half2float(h2[(q0.z << 6) + lane]);
            float r3  = __half2float(h2[(q0.w << 6) + lane]);
            float r4  = __half2float(h2[(q1.x << 6) + lane]);
            float r5  = __half2float(h2[(q1.y << 6) + lane]);
            float r6  = __half2float(h2[(q1.z << 6) + lane]);
            float r7  = __half2float(h2[(q1.w << 6) + lane]);
            float r8  = __half2float(h2[(q2.x << 6) + lane]);
            float r9  = __half2float(h2[(q2.y << 6) + lane]);
            float r10 = __half2float(h2[(q2.z << 6) + lane]);
            float r11 = __half2float(h2[(q2.w << 6) + lane]);
            float r12 = __half2float(h2[(q3.x << 6) + lane]);
            float r13 = __half2float(h2[(q3.y << 6) + lane]);
            float r14 = __half2float(h2[(q3.z << 6) + lane]);
            float r15 = __half2float(h2[(q3.w << 6) + lane]);
            float r16 = __half2float(h2[(q4.x << 6) + lane]);
            float r17 = __half2float(h2[(q4.y << 6) + lane]);
            float r18 = __half2float(h2[(q4.z << 6) + lane]);
            float r19 = __half2float(h2[(q4.w << 6) + lane]);
            float r20 = __half2float(h2[(q5.x << 6) + lane]);
            float r21 = __half2float(h2[(q5.y << 6) + lane]);
            float r22 = __half2float(h2[(q5.z << 6) + lane]);
            float r23 = __half2float(h2[(q5.w << 6) + lane]);
            float r24 = __half2float(h2[(q6.x << 6) + lane]);
            float r25 = __half2float(h2[(q6.y << 6) + lane]);
            float r26 = __half2float(h2[(q6.z << 6) + lane]);
            float r27 = __half2float(h2[(q6.w << 6) + lane]);
            float r28 = __half2float(h2[(q7.x << 6) + lane]);
            float r29 = __half2float(h2[(q7.y << 6) + lane]);
            float r30 = __half2float(h2[(q7.z << 6) + lane]);
            float r31 = __half2float(h2[(q7.w << 6) + lane]);
            acc += ((((r0 + r1) + (r2 + r3)) + ((r4 + r5) + (r6 + r7)))
                  + (((r8 + r9) + (r10 + r11)) + ((r12 + r13) + (r14 + r15))))
                 + ((((r16 + r17) + (r18 + r19)) + ((r20 + r21) + (r22 + r23)))
                  + (((r24 + r25) + (r26 + r27)) + ((r28 + r29) + (r30 + r31))));
        }
        if (e + 16 <= k1) {
            const int4* ep = (const int4*)(esrc + e);
            int4 qa = ep[0], qb = ep[1], qc = ep[2], qd = ep[3];
            float r0 = __half2float(h2[(qa.x << 6) + lane]);
            float r1 = __half2float(h2[(qa.y << 6) + lane]);
            float r2 = __half2float(h2[(qa.z << 6) + lane]);
            float r3 = __half2float(h2[(qa.w << 6) + lane]);
            float r4 = __half2float(h2[(qb.x << 6) + lane]);
            float r5 = __half2float(h2[(qb.y << 6) + lane]);
            float r6 = __half2float(h2[(qb.z << 6) + lane]);
            float r7 = __half2float(h2[(qb.w << 6) + lane]);
            float r8 = __half2float(h2[(qc.x << 6) + lane]);
            float r9 = __half2float(h2[(qc.y << 6) + lane]);
            float r10 = __half2float(h2[(qc.z << 6) + lane]);
            float r11 = __half2float(h2[(qc.w << 6) + lane]);
            float r12 = __half2float(h2[(qd.x << 6) + lane]);
            float r13 = __half2float(h2[(qd.y << 6) + lane]);
            float r14 = __half2float(h2[(qd.z << 6) + lane]);
            float r15 = __half2float(h2[(qd.w << 6) + lane]);
            acc += (((r0 + r1) + (r2 + r3)) + ((r4 + r5) + (r6 + r7)))
                 + (((r8 + r9) + (r10 + r11)) + ((r12 + r13) + (r14 + r15)));
            e += 16;
        }
        if (e < k1) {  // exactly 8 remain
            const int4* ep = (const int4*)(esrc + e);
            int4 qa = ep[0], qb = ep[1];
            float r0 = __half2float(h2[(qa.x << 6) + lane]);
            float r1 = __half2float(h2[(qa.y << 6) + lane]);
            float r2 = __half2float(h2[(qa.z << 6) + lane]);
            float r3 = __half2float(h2[(qa.w << 6) + lane]);
            float r4 = __half2float(h2[(qb.x << 6) + lane]);
            float r5 = __half2float(h2[(qb.y << 6) + lane]);
            float r6 = __half2float(h2[(qb.z << 6) + lane]);
            float r7 = __half2float(h2[(qb.w << 6) + lane]);
            acc += ((r0 + r1) + (r2 + r3)) + ((r4 + r5) + (r6 + r7));
        }
        float z = fmaxf(fmaf(dinv[un], acc, bz), 0.0f);
        int g = __builtin_amdgcn_readfirstlane(batch[un]);
        if (g != gcur) {
            if (gcur >= 0) atomicAdd(&gsum[(gcur << 6) + lane], zacc);
            gcur = g;
            zacc = 0.0f;
        }
        zacc += z;
    }
    if (gcur >= 0) atomicAdd(&gsum[(gcur << 6) + lane], zacc);
}

// ---------------- head ----------------
__global__ void head_kernel(const float* __restrict__ gsum, const int* __restrict__ gstart,
                            const float* __restrict__ Wf1, const float* __restrict__ bf1,
                            const float* __restrict__ Wf2, const float* __restrict__ bf2,
                            float* __restrict__ out) {
    __shared__ float gs[HID];
    __shared__ float ts[HID];
    int b = blockIdx.x;
    int j = threadIdx.x;
    float cnt = fmaxf((float)(gstart[b + 1] - gstart[b]), 1.0f);
    gs[j] = gsum[b * HID + j] / cnt;
    __syncthreads();
    float acc = bf1[j];
#pragma unroll
    for (int k = 0; k < HID; ++k) acc = fmaf(gs[k], Wf1[k * HID + j], acc);
    ts[j] = fmaxf(acc, 0.0f);
    __syncthreads();
    if (j < 4) {
        float o = bf2[j];
#pragma unroll
        for (int k = 0; k < HID; ++k) o = fmaf(ts[k], Wf2[k * 4 + j], o);
        out[b * 4 + j] = o;
    }
}

extern "C" void kernel_launch(void* const* d_in, const int* in_sizes, int n_in,
                              void* d_out, int out_size, void* d_ws, size_t ws_size,
                              hipStream_t stream) {
    const float* x   = (const float*)d_in[0];
    const int*   ei  = (const int*)d_in[1];
    const int*   bat = (const int*)d_in[2];
    const float* W1  = (const float*)d_in[4];
    const float* b1  = (const float*)d_in[5];
    const float* W2  = (const float*)d_in[6];
    const float* b2  = (const float*)d_in[7];
    const float* Wf1 = (const float*)d_in[8];
    const float* bf1 = (const float*)d_in[9];
    const float* Wf2 = (const float*)d_in[10];
    const float* bf2 = (const float*)d_in[11];
    float* out = (float*)d_out;

    int N = in_sizes[2];
    int E = in_sizes[1] / 2;
    const int* src = ei;
    const int* dst = ei + E;
    int nbc = (N + BKT - 1) >> CSH;               // coarse buckets (<= MAXB)
    int ntile = (E + PTILE - 1) / PTILE;
    int S = 2 * (E / nbc) + 1024;                 // fixed bucket stride (2x mean margin)
    size_t Ecap = ((size_t)E + 7 * (size_t)N + 8 + 3) & ~(size_t)3;  // padded upper bound

    char* ws = (char*)d_ws;
    size_t off = 0;
    auto alloc = [&](size_t bytes) {
        char* p = ws + off;
        off = (off + bytes + 255) & ~(size_t)255;
        return p;
    };
    int*    bcnt   = (int*)alloc((size_t)MAXB * 4);
    int*    ecur   = (int*)alloc(256);                       // global esrc cursor
    float*  gsum   = (float*)alloc((size_t)NG * HID * 4);    // contiguous with bcnt/ecur
    int*    deg    = (int*)alloc((size_t)N * 4);
    float*  dinv   = (float*)alloc((size_t)N * 4);
    int*    rowbeg = (int*)alloc((size_t)N * 4);
    int*    esrc   = (int*)alloc(Ecap * 4);
    int*    pstage = (int*)alloc((size_t)nbc * S * 4);
    float2* xs2    = (float2*)alloc((size_t)(N + 1) * 8);
    __half* h2buf  = (__half*)alloc((size_t)(N + 1) * HID * 2);
    int*    gstart = (int*)alloc((size_t)(NG + 1) * 4);

    // bcnt, ecur, gsum contiguous -> single memset clears all three
    hipMemsetAsync(bcnt, 0, (size_t)((char*)gsum - (char*)bcnt) + (size_t)NG * HID * 4,
                   stream);

    partA_kernel<<<ntile, 256, 0, stream>>>(src, dst, bat, gstart, bcnt, pstage, E, N,
                                            nbc, S);
    partB2_kernel<<<nbc, 256, 0, stream>>>(pstage, bcnt, (const float2*)x, deg, dinv, xs2,
                                           rowbeg, esrc, ecur, h2buf, N, S);

    // layer1f: fused gather+W1 -> LDS tile -> @W2 -> fp16 h2 (no h1buf)
    layer1f_kernel<<<(N + TNB - 1) / TNB, 256, 0, stream>>>(xs2, rowbeg, deg, esrc, dinv,
                                                            W1, b1, W2, h2buf, N);

    // layer 2: fp16 gather-sum -> relu -> graph-run pooled atomics
    layer2_kernel<<<4096, 256, 0, stream>>>(rowbeg, deg, esrc, dinv, h2buf, b2, bat, gsum,
                                            N);

    head_kernel<<<NG, HID, 0, stream>>>(gsum, gstart, Wf1, bf1, Wf2, bf2, out);
}

// Round 14
// 222.719 us; speedup vs baseline: 1.0667x; 1.0667x over previous
//
#include <hip/hip_runtime.h>
#include <hip/hip_fp16.h>

#define NG 512
#define HID 64
#define CSH 9                 // coarse-bucket shift: 512 nodes/bucket
#define BKT (1 << CSH)
#define PTILE 4096            // partA edges per block
#define MAXB 1024             // max coarse buckets (N up to 512k)
#define TNB 128               // l1gemm node tile

// Each node's CSR segment is padded to a multiple of 8; pad slots hold src=N,
// which indexes a zero row in xs2 / h2, so pads contribute nothing.
__device__ __forceinline__ int pad8(int d) { return (d + 7) & ~7; }

// ---------------- partA: coarse partition into fixed-stride pstage ----------
// pstage entry = (src << CSH) | (dst & (BKT-1)) : 4B. Fixed per-bucket stride
// S lets buckets claim runs with ONE global atomicAdd on bcnt[]. gstart
// (batch sorted; boundary detection) folded in as latency-filler work.
__global__ __launch_bounds__(256) void partA_kernel(
    const int* __restrict__ src, const int* __restrict__ dst,
    const int* __restrict__ batch, int* __restrict__ gstart,
    int* __restrict__ bcnt, int* __restrict__ pstage,
    int E, int N, int nbc, int S) {
    __shared__ int hist[MAXB];
    __shared__ int base[MAXB];
    int tid = threadIdx.x;
    int t0 = blockIdx.x * PTILE;
    for (int i = blockIdx.x * 256 + tid; i < N; i += gridDim.x * 256) {
        int b = batch[i];
        int bp = (i == 0) ? -1 : batch[i - 1];
        for (int g = bp + 1; g <= b; ++g) gstart[g] = i;   // boundaries only
        if (i == N - 1)
            for (int g = b + 1; g <= NG; ++g) gstart[g] = N;
    }
    for (int i = tid; i < nbc; i += 256) hist[i] = 0;
    __syncthreads();
    int es[PTILE / 256], ds[PTILE / 256];
#pragma unroll
    for (int j = 0; j < PTILE / 256; ++j) {
        int e = t0 + j * 256 + tid;
        if (e < E) {
            ds[j] = dst[e];
            es[j] = src[e];
            atomicAdd(&hist[ds[j] >> CSH], 1);
        } else {
            ds[j] = -1;
        }
    }
    __syncthreads();
    for (int i = tid; i < nbc; i += 256) {
        int c = hist[i];
        base[i] = c ? atomicAdd(&bcnt[i], c) : 0;
        hist[i] = 0;  // reuse as tile-local cursor
    }
    __syncthreads();
#pragma unroll
    for (int j = 0; j < PTILE / 256; ++j) {
        if (ds[j] >= 0) {
            int b = ds[j] >> CSH;
            int r = base[b] + atomicAdd(&hist[b], 1);
            if (r < S)  // guard (never fires for uniform-random dst)
                pstage[(size_t)b * S + r] = (es[j] << CSH) | (ds[j] & (BKT - 1));
        }
    }
}

// ---------------- partB2: per-bucket deg/dinv/xs2 + rowbeg + scatter + pads --
// One block per bucket; single-writer esrc window (no write amplification).
// Also zeroes the h2 pad row (block 0) so the second host memset is gone.
__global__ __launch_bounds__(256) void partB2_kernel(
    const int* __restrict__ pstage, const int* __restrict__ bcnt,
    const float2* __restrict__ x2, int* __restrict__ deg, float* __restrict__ dinv,
    float2* __restrict__ xs2, int* __restrict__ rowbeg, int* __restrict__ esrc,
    int* __restrict__ ecur, __half* __restrict__ h2, int N, int S) {
    __shared__ int h[BKT];
    __shared__ int rowL[BKT];
    __shared__ int curL[BKT];
    __shared__ int ps[256];
    __shared__ int baseS;
    int c = blockIdx.x;
    int n0 = c << CSH;
    int tid = threadIdx.x;
    for (int i = tid; i < BKT; i += 256) h[i] = 0;
    __syncthreads();
    int cnt = min(bcnt[c], S);
    const int* pst = pstage + (size_t)c * S;
    for (int i = tid; i < cnt; i += 256) atomicAdd(&h[pst[i] & (BKT - 1)], 1);
    __syncthreads();
    int i0 = 2 * tid, i1 = 2 * tid + 1;
    int dg0 = (n0 + i0 < N) ? h[i0] : 0;
    int dg1 = (n0 + i1 < N) ? h[i1] : 0;
    if (n0 + i0 < N) {
        deg[n0 + i0] = dg0;
        float di = rsqrtf((float)dg0 + 1.0f);
        dinv[n0 + i0] = di;
        float2 xv = x2[n0 + i0];
        xs2[n0 + i0] = make_float2(xv.x * di, xv.y * di);
    }
    if (n0 + i1 < N) {
        deg[n0 + i1] = dg1;
        float di = rsqrtf((float)dg1 + 1.0f);
        dinv[n0 + i1] = di;
        float2 xv = x2[n0 + i1];
        xs2[n0 + i1] = make_float2(xv.x * di, xv.y * di);
    }
    int p0 = pad8(dg0), p1 = pad8(dg1);
    ps[tid] = p0 + p1;
    __syncthreads();
    for (int off = 1; off < 256; off <<= 1) {
        int t = (tid >= off) ? ps[tid - off] : 0;
        __syncthreads();
        ps[tid] += t;
        __syncthreads();
    }
    if (tid == 255) baseS = atomicAdd(ecur, ps[255]);  // claim bucket's esrc span
    __syncthreads();
    int excl = baseS + ps[tid] - (p0 + p1);
    rowL[i0] = excl;
    rowL[i1] = excl + p0;
    curL[i0] = 0;
    curL[i1] = 0;
    if (n0 + i0 < N) rowbeg[n0 + i0] = rowL[i0];
    if (n0 + i1 < N) rowbeg[n0 + i1] = rowL[i1];
    __syncthreads();
    for (int i = tid; i < cnt; i += 256) {
        int w = pst[i];
        int l = w & (BKT - 1);
        int p = rowL[l] + atomicAdd(&curL[l], 1);
        esrc[p] = w >> CSH;
    }
    __syncthreads();
    for (int l = tid; l < BKT; l += 256) {
        if (n0 + l < N) {
            int dg = curL[l];                  // == deg
            int p = rowL[l] + dg, p1e = rowL[l] + pad8(dg);
            for (; p < p1e; ++p) esrc[p] = N;  // pads -> zero row (<=7 per node)
        }
    }
    if (c == 0) {
        if (tid == 0) xs2[N] = make_float2(0.0f, 0.0f);
        if (tid < 8)  // zero h2 pad row (128B) -> replaces host memset
            ((int4*)(h2 + (size_t)N * HID))[tid] = make_int4(0, 0, 0, 0);
    }
}

// ---------------- layer 1a: gather + W1 -> h1s (fp16) -----------------------
// One wave per node (~100k waves: the MLP that layer1f's 6k waves lost, R12
// post-mortem). fp16 output halves the h1buf round-trip (R12's only real
// win, kept without the fusion).
__global__ __launch_bounds__(256) void layer1a_kernel(
    const float2* __restrict__ xs2, const int* __restrict__ rowbeg,
    const int* __restrict__ deg, const int* __restrict__ esrc,
    const float* __restrict__ dinv, const float* __restrict__ W1,
    const float* __restrict__ b1, __half* __restrict__ h1s, int N) {
    int t = blockIdx.x * blockDim.x + threadIdx.x;
    int node = t >> 6, lane = t & 63;
    if (node >= N) return;
    int un = __builtin_amdgcn_readfirstlane(node);
    int k0 = __builtin_amdgcn_readfirstlane(rowbeg[un]);
    int k1 = k0 + pad8(__builtin_amdgcn_readfirstlane(deg[un]));
    float a0 = 0.0f, a1 = 0.0f;
    for (int e = k0; e < k1; e += 8) {
        const int4* ep = (const int4*)(esrc + e);  // 32B-aligned (rowbeg % 8 == 0)
        int4 qa = ep[0], qb = ep[1];
        float2 v0 = xs2[qa.x], v1 = xs2[qa.y], v2 = xs2[qa.z], v3 = xs2[qa.w];
        float2 v4 = xs2[qb.x], v5 = xs2[qb.y], v6 = xs2[qb.z], v7 = xs2[qb.w];
        a0 += ((v0.x + v1.x) + (v2.x + v3.x)) + ((v4.x + v5.x) + (v6.x + v7.x));
        a1 += ((v0.y + v1.y) + (v2.y + v3.y)) + ((v4.y + v5.y) + (v6.y + v7.y));
    }
    float di = dinv[un];
    float2 xn = xs2[un];
    float m0 = di * (a0 + xn.x);  // = di*sum(x_s*di_s) + x_n*di^2
    float m1 = di * (a1 + xn.y);
    float v = fmaf(m0, W1[lane], fmaf(m1, W1[HID + lane], b1[lane]));
    h1s[(size_t)un * HID + lane] = __float2half_rn(fmaxf(v, 0.0f) * di);
}

// ---------------- l1gemm: h2 = h1s(fp16) @ W2 (fp16 out), 128-node tiles ----
// Staging unpacks fp16 h1 into the fp32 swizzled LDS tile; compute phase is
// the identical ascending-k scalarized GEMM (R11 numerics + one h1 quantize).
__global__ __launch_bounds__(TNB) void l1gemm_kernel(
    const __half* __restrict__ h1s, const float* __restrict__ W2,
    __half* __restrict__ h2, int N) {
    __shared__ float h1t[HID * TNB];  // 32KB, [k][node-swizzled]
    int t = threadIdx.x;
    int node0 = blockIdx.x * TNB;
    const int4* g4 = (const int4*)h1s;  // int4 = 8 halves
#pragma unroll
    for (int r = 0; r < 8; ++r) {
        int g = r * TNB + t;          // int4 index within tile
        int nd = g >> 3, kq = g & 7;  // node, 8-half group
        int4 v = make_int4(0, 0, 0, 0);
        if (node0 + nd < N) v = g4[(size_t)(node0 + nd) * 8 + kq];
        const __half* hp = (const __half*)&v;
        int kb = kq * 8;
#pragma unroll
        for (int u = 0; u < 8; ++u)
            h1t[(kb + u) * TNB + (nd ^ ((kb + u) & 31))] = __half2float(hp[u]);
    }
    __syncthreads();
    int node = node0 + t;
    bool alive = node < N;
#pragma unroll 1
    for (int jt = 0; jt < 8; ++jt) {
        float c0 = 0.f, c1 = 0.f, c2 = 0.f, c3 = 0.f;
        float c4 = 0.f, c5 = 0.f, c6 = 0.f, c7 = 0.f;
#pragma unroll 8
        for (int k = 0; k < HID; ++k) {  // ascending k: same fma order as R11
            float h = h1t[k * TNB + (t ^ (k & 31))];
            const float4* wr = (const float4*)(W2 + k * HID + jt * 8);  // uniform
            float4 wa = wr[0], wb = wr[1];
            c0 = fmaf(h, wa.x, c0); c1 = fmaf(h, wa.y, c1);
            c2 = fmaf(h, wa.z, c2); c3 = fmaf(h, wa.w, c3);
            c4 = fmaf(h, wb.x, c4); c5 = fmaf(h, wb.y, c5);
            c6 = fmaf(h, wb.z, c6); c7 = fmaf(h, wb.w, c7);
        }
        if (alive) {
            union { __half h[8]; int4 v; } u;
            u.h[0] = __float2half_rn(c0); u.h[1] = __float2half_rn(c1);
            u.h[2] = __float2half_rn(c2); u.h[3] = __float2half_rn(c3);
            u.h[4] = __float2half_rn(c4); u.h[5] = __float2half_rn(c5);
            u.h[6] = __float2half_rn(c6); u.h[7] = __float2half_rn(c7);
            *(int4*)(h2 + (size_t)node * HID + jt * 8) = u.v;
        }
    }
}

// ---------------- layer 2: fp16 gather-sum + graph-run pooled atomics -------
__global__ __launch_bounds__(256, 8) void layer2_kernel(
    const int* __restrict__ rowbeg, const int* __restrict__ deg,
    const int* __restrict__ esrc, const float* __restrict__ dinv,
    const __half* __restrict__ h2, const float* __restrict__ b2,
    const int* __restrict__ batch, float* __restrict__ gsum, int N) {
    int lane = threadIdx.x & 63;
    float bz = b2[lane];
    int wave = (blockIdx.x * 256 + threadIdx.x) >> 6;
    int nwaves = gridDim.x * 4;
    int npw = (N + nwaves - 1) / nwaves;
    int nA = wave * npw;
    int nB = min(N, nA + npw);
    int gcur = -1;
    float zacc = 0.0f;
    for (int node = nA; node < nB; ++node) {
        int un = __builtin_amdgcn_readfirstlane(node);
        int k0 = __builtin_amdgcn_readfirstlane(rowbeg[un]);
        int k1 = k0 + pad8(__builtin_amdgcn_readfirstlane(deg[un]));
        float acc = __half2float(h2[(un << 6) + lane]);  // self term
        int e = k0;
        for (; e + 32 <= k1; e += 32) {
            const int4* ep = (const int4*)(esrc + e);
            int4 q0 = ep[0], q1 = ep[1], q2 = ep[2], q3 = ep[3];
            int4 q4 = ep[4], q5 = ep[5], q6 = ep[6], q7 = ep[7];
            float r0  = __half2float(h2[(q0.x << 6) + lane]);
            float r1  = __half2float(h2[(q0.y << 6) + lane]);
            float r2  = __half2float(h2[(q0.z << 6) + lane]);
            float r3  = __half2float(h2[(q0.w << 6) + lane]);
            float r4  = __half2float(h2[(q1.x << 6) + lane]);
            float r5  = __half2float(h2[(q1.y << 6) + lane]);
            float r6  = __half2float(h2[(q1.z << 6) + lane]);
            float r7  = __half2float(h2[(q1.w << 6) + lane]);
            float r8  = __half2float(h2[(q2.x << 6) + lane]);
            float r9  = __half2float(h2[(q2.y << 6) + lane]);
            float r10 = __half2float(h2[(q2.z << 6) + lane]);
            float r11 = __half2float(h2[(q2.w << 6) + lane]);
            float r12 = __half2float(h2[(q3.x << 6) + lane]);
            float r13 = __half2float(h2[(q3.y << 6) + lane]);
            float r14 = __half2float(h2[(q3.z << 6) + lane]);
            float r15 = __half2float(h2[(q3.w << 6) + lane]);
            float r16 = __half2float(h2[(q4.x << 6) + lane]);
            float r17 = __half2float(h2[(q4.y << 6) + lane]);
            float r18 = __half2float(h2[(q4.z << 6) + lane]);
            float r19 = __half2float(h2[(q4.w << 6) + lane]);
            float r20 = __half2float(h2[(q5.x << 6) + lane]);
            float r21 = __half2float(h2[(q5.y << 6) + lane]);
            float r22 = __half2float(h2[(q5.z << 6) + lane]);
            float r23 = __half2float(h2[(q5.w << 6) + lane]);
            float r24 = __half2float(h2[(q6.x << 6) + lane]);
            float r25 = __half2float(h2[(q6.y << 6) + lane]);
            float r26 = __half2float(h2[(q6.z << 6) + lane]);
            float r27 = __half2float(h2[(q6.w << 6) + lane]);
            float r28 = __half2float(h2[(q7.x << 6) + lane]);
            float r29 = __half2float(h2[(q7.y << 6) + lane]);
            float r30 = __half2float(h2[(q7.z << 6) + lane]);
            float r31 = __half2float(h2[(q7.w << 6) + lane]);
            acc += ((((r0 + r1) + (r2 + r3)) + ((r4 + r5) + (r6 + r7)))
                  + (((r8 + r9) + (r10 + r11)) + ((r12 + r13) + (r14 + r15))))
                 + ((((r16 + r17) + (r18 + r19)) + ((r20 + r21) + (r22 + r23)))
                  + (((r24 + r25) + (r26 + r27)) + ((r28 + r29) + (r30 + r31))));
        }
        if (e + 16 <= k1) {
            const int4* ep = (const int4*)(esrc + e);
            int4 qa = ep[0], qb = ep[1], qc = ep[2], qd = ep[3];
            float r0 = __half2float(h2[(qa.x << 6) + lane]);
            float r1 = __half2float(h2[(qa.y << 6) + lane]);
            float r2 = __half2float(h2[(qa.z << 6) + lane]);
            float r3 = __half2float(h2[(qa.w << 6) + lane]);
            float r4 = __half2float(h2[(qb.x << 6) + lane]);
            float r5 = __half2float(h2[(qb.y << 6) + lane]);
            float r6 = __half2float(h2[(qb.z << 6) + lane]);
            float r7 = __half2float(h2[(qb.w << 6) + lane]);
            float r8 = __half2float(h2[(qc.x << 6) + lane]);
            float r9 = __half2float(h2[(qc.y << 6) + lane]);
            float r10 = __half2float(h2[(qc.z << 6) + lane]);
            float r11 = __half2float(h2[(qc.w << 6) + lane]);
            float r12 = __half2float(h2[(qd.x << 6) + lane]);
            float r13 = __half2float(h2[(qd.y << 6) + lane]);
            float r14 = __half2float(h2[(qd.z << 6) + lane]);
            float r15 = __half2float(h2[(qd.w << 6) + lane]);
            acc += (((r0 + r1) + (r2 + r3)) + ((r4 + r5) + (r6 + r7)))
                 + (((r8 + r9) + (r10 + r11)) + ((r12 + r13) + (r14 + r15)));
            e += 16;
        }
        if (e < k1) {  // exactly 8 remain
            const int4* ep = (const int4*)(esrc + e);
            int4 qa = ep[0], qb = ep[1];
            float r0 = __half2float(h2[(qa.x << 6) + lane]);
            float r1 = __half2float(h2[(qa.y << 6) + lane]);
            float r2 = __half2float(h2[(qa.z << 6) + lane]);
            float r3 = __half2float(h2[(qa.w << 6) + lane]);
            float r4 = __half2float(h2[(qb.x << 6) + lane]);
            float r5 = __half2float(h2[(qb.y << 6) + lane]);
            float r6 = __half2float(h2[(qb.z << 6) + lane]);
            float r7 = __half2float(h2[(qb.w << 6) + lane]);
            acc += ((r0 + r1) + (r2 + r3)) + ((r4 + r5) + (r6 + r7));
        }
        float z = fmaxf(fmaf(dinv[un], acc, bz), 0.0f);
        int g = __builtin_amdgcn_readfirstlane(batch[un]);
        if (g != gcur) {
            if (gcur >= 0) atomicAdd(&gsum[(gcur << 6) + lane], zacc);
            gcur = g;
            zacc = 0.0f;
        }
        zacc += z;
    }
    if (gcur >= 0) atomicAdd(&gsum[(gcur << 6) + lane], zacc);
}

// ---------------- head ----------------
__global__ void head_kernel(const float* __restrict__ gsum, const int* __restrict__ gstart,
                            const float* __restrict__ Wf1, const float* __restrict__ bf1,
                            const float* __restrict__ Wf2, const float* __restrict__ bf2,
                            float* __restrict__ out) {
    __shared__ float gs[HID];
    __shared__ float ts[HID];
    int b = blockIdx.x;
    int j = threadIdx.x;
    float cnt = fmaxf((float)(gstart[b + 1] - gstart[b]), 1.0f);
    gs[j] = gsum[b * HID + j] / cnt;
    __syncthreads();
    float acc = bf1[j];
#pragma unroll
    for (int k = 0; k < HID; ++k) acc = fmaf(gs[k], Wf1[k * HID + j], acc);
    ts[j] = fmaxf(acc, 0.0f);
    __syncthreads();
    if (j < 4) {
        float o = bf2[j];
#pragma unroll
        for (int k = 0; k < HID; ++k) o = fmaf(ts[k], Wf2[k * 4 + j], o);
        out[b * 4 + j] = o;
    }
}

extern "C" void kernel_launch(void* const* d_in, const int* in_sizes, int n_in,
                              void* d_out, int out_size, void* d_ws, size_t ws_size,
                              hipStream_t stream) {
    const float* x   = (const float*)d_in[0];
    const int*   ei  = (const int*)d_in[1];
    const int*   bat = (const int*)d_in[2];
    const float* W1  = (const float*)d_in[4];
    const float* b1  = (const float*)d_in[5];
    const float* W2  = (const float*)d_in[6];
    const float* b2  = (const float*)d_in[7];
    const float* Wf1 = (const float*)d_in[8];
    const float* bf1 = (const float*)d_in[9];
    const float* Wf2 = (const float*)d_in[10];
    const float* bf2 = (const float*)d_in[11];
    float* out = (float*)d_out;

    int N = in_sizes[2];
    int E = in_sizes[1] / 2;
    const int* src = ei;
    const int* dst = ei + E;
    int nbc = (N + BKT - 1) >> CSH;               // coarse buckets (<= MAXB)
    int ntile = (E + PTILE - 1) / PTILE;
    int S = 2 * (E / nbc) + 1024;                 // fixed bucket stride (2x mean margin)
    size_t Ecap = ((size_t)E + 7 * (size_t)N + 8 + 3) & ~(size_t)3;  // padded upper bound

    char* ws = (char*)d_ws;
    size_t off = 0;
    auto alloc = [&](size_t bytes) {
        char* p = ws + off;
        off = (off + bytes + 255) & ~(size_t)255;
        return p;
    };
    int*    bcnt   = (int*)alloc((size_t)MAXB * 4);
    int*    ecur   = (int*)alloc(256);                       // global esrc cursor
    float*  gsum   = (float*)alloc((size_t)NG * HID * 4);    // contiguous with bcnt/ecur
    int*    deg    = (int*)alloc((size_t)N * 4);
    float*  dinv   = (float*)alloc((size_t)N * 4);
    int*    rowbeg = (int*)alloc((size_t)N * 4);
    int*    esrc   = (int*)alloc(Ecap * 4);
    int*    pstage = (int*)alloc((size_t)nbc * S * 4);
    float2* xs2    = (float2*)alloc((size_t)(N + 1) * 8);
    __half* h1buf  = (__half*)alloc((size_t)N * HID * 2);
    __half* h2buf  = (__half*)alloc((size_t)(N + 1) * HID * 2);
    int*    gstart = (int*)alloc((size_t)(NG + 1) * 4);

    // bcnt, ecur, gsum contiguous -> single memset clears all three
    hipMemsetAsync(bcnt, 0, (size_t)((char*)gsum - (char*)bcnt) + (size_t)NG * HID * 4,
                   stream);

    partA_kernel<<<ntile, 256, 0, stream>>>(src, dst, bat, gstart, bcnt, pstage, E, N,
                                            nbc, S);
    partB2_kernel<<<nbc, 256, 0, stream>>>(pstage, bcnt, (const float2*)x, deg, dinv, xs2,
                                           rowbeg, esrc, ecur, h2buf, N, S);

    // layer 1a: gather + W1 -> h1s (fp16, one wave per node)
    int nh = N * HID;
    layer1a_kernel<<<(nh + 255) / 256, 256, 0, stream>>>(xs2, rowbeg, deg, esrc, dinv, W1,
                                                         b1, h1buf, N);
    // l1gemm: h2 = h1s @ W2 (fp16 in/out)
    l1gemm_kernel<<<(N + TNB - 1) / TNB, TNB, 0, stream>>>(h1buf, W2, h2buf, N);

    // layer 2: fp16 gather-sum -> relu -> graph-run pooled atomics
    layer2_kernel<<<4096, 256, 0, stream>>>(rowbeg, deg, esrc, dinv, h2buf, b2, bat, gsum,
                                            N);

    head_kernel<<<NG, HID, 0, stream>>>(gsum, gstart, Wf1, bf1, Wf2, bf2, out);
}